// Round 4
// baseline (453.827 us; speedup 1.0000x reference)
//
#include <hip/hip_runtime.h>
#include <hip/hip_bf16.h>

// Problem constants
#define TDATA 100000
#define NE 500
#define NI 200
#define SUB 20
#define NB 3
#define TSYN 201

// Layout
#define SROW 100552              // 200 front pad + data + tail pad
#define HROW 216                 // conv taps padded: k in [-8,207] at [k+8]
#define STEPS_E 32               // K_e padded to 512
#define STEPS_I 13               // K_i padded to 208
#define GEMM_BLKS 3125           // 100000/32 row-tiles per matrix (exact)

// ws float offsets
#define OFF_HP  0                            // 2*20*216 = 8640 floats
#define OFF_BE  8640                         // e A-frags: 32*64*8 bf16 = 8192 float slots
#define OFF_BI  (OFF_BE + 8192)              // 16832; i A-frags: 13*64*8 bf16 = 3328 slots
#define OFF_INT (OFF_BI + 3328)              // 20160, inT = 40 rows x SROW

typedef __bf16 bf16x8 __attribute__((ext_vector_type(8)));
typedef float  f32x16 __attribute__((ext_vector_type(16)));

// ---------------------------------------------------------------------------
// Setup: conv taps | inT pad zeros | bf16 A-operand fragments (verified MFMA
// lane order: element j of lane l, k-step u  ->  C[s=l&31][k=16u+8*(l>>5)+j])
// ---------------------------------------------------------------------------
__global__ __launch_bounds__(256) void setup_kernel(
    const float* __restrict__ C_e, const float* __restrict__ C_i,
    const float* __restrict__ K_syn, const float* __restrict__ tau_syn,
    const float* __restrict__ delta_syn, float* __restrict__ ws)
{
    int idx = blockIdx.x * 256 + threadIdx.x;
    if (idx < 8640) {                        // ---- conv taps (zero-padded)
        int c = idx / (SUB * HROW);
        int rem = idx - c * (SUB * HROW);
        int s = rem / HROW;
        int k = (rem - s * HROW) - 8;
        float v = 0.f;
        if (k >= 0 && k < TSYN) {
            float ts = (float)k - delta_syn[s * 2 + c];
            ts = ts < 0.f ? 0.f : ts;
            #pragma unroll
            for (int b = 0; b < NB; b++) {
                float tt = ts / expf(tau_syn[b * 2 + c]);
                v += K_syn[(s * NB + b) * 2 + c] * tt * expf(-tt);
            }
        }
        ws[OFF_HP + idx] = v;
    } else if (idx < 30720) {                // ---- inT front/tail pad zeros
        int j = idx - 8640;
        const int PERROW = 552;              // 200 front + 352 tail
        int row = j / PERROW;
        int e = j - row * PERROW;
        int off = (e < 200) ? e : (200 + TDATA + (e - 200));
        ws[OFF_INT + (long)row * SROW + off] = 0.f;
    } else if (idx < 47104) {                // ---- e A-frags (bf16)
        int j = idx - 30720;                 // 32*64*8 = 16384
        int step = j >> 9;
        int lane = (j >> 3) & 63;
        int jj = j & 7;
        int k = step * 16 + ((lane >> 5) << 3) + jj;
        int s = lane & 31;
        float v = (s < SUB && k < NE) ? C_e[s * NE + k] : 0.f;
        ((__hip_bfloat16*)(ws + OFF_BE))[j] = (__hip_bfloat16)v;
    } else {                                 // ---- i A-frags (bf16)
        int j = idx - 47104;                 // 13*64*8 = 6656
        int step = j >> 9;
        int lane = (j >> 3) & 63;
        int jj = j & 7;
        int k = step * 16 + ((lane >> 5) << 3) + jj;
        int s = lane & 31;
        float v = (s < SUB && k < NI) ? C_i[s * NI + k] : 0.f;
        ((__hip_bfloat16*)(ws + OFF_BI))[j] = (__hip_bfloat16)v;
    }
}

// ---------------------------------------------------------------------------
// MFMA GEMM, coalesced-staging version. Block = 32 contiguous S rows (the
// 64 KB / 25.6 KB row-block is CONTIGUOUS in global memory). All staging
// loads are perfectly coalesced float4. 4 waves split K; cross-wave
// reduction via LDS; wave 0 stores D (verified layout).
// Blocks [0,3125) -> e, [3125,6250) -> i.
// ---------------------------------------------------------------------------
__global__ __launch_bounds__(256) void gemm_kernel(
    const float* __restrict__ Se, const float* __restrict__ Si,
    float* __restrict__ ws)
{
    __shared__ float lds[16016];             // 64,064 B (<= 64 KB static limit)
    const int tid  = threadIdx.x;
    const int lane = tid & 63, w = tid >> 6;
    const bool isE = blockIdx.x < GEMM_BLKS;
    const int blk  = isE ? blockIdx.x : blockIdx.x - GEMM_BLKS;
    const float* S = isE ? Se : Si;
    const int KROW = isE ? NE : NI;
    const int NV4  = isE ? 4000 : 1600;      // float4 count of the row-block
    const int ZTAIL = isE ? 16000 : 6400;    // first garbage-read float index
    const float* afr_base = ws + (isE ? OFF_BE : OFF_BI);
    float* inT = ws + OFF_INT + (isE ? 0 : (long)SUB * SROW);
    const long row0 = (long)blk * 32;

    // wave's k-step range
    int u0, u1;
    if (isE) { u0 = 8 * w; u1 = u0 + 8; }
    else     { u0 = (w == 0) ? 0 : (w == 1) ? 4 : (w == 2) ? 7 : 10;
               u1 = (w == 0) ? 4 : (w == 1) ? 7 : (w == 2) ? 10 : 13; }

    // prefetch this wave's A-fragments (independent of LDS staging)
    const bf16x8* afr = (const bf16x8*)afr_base;
    bf16x8 af[8];
    #pragma unroll
    for (int p = 0; p < 8; p++) {
        int u = u0 + p;
        if (u < u1) af[p] = afr[u * 64 + lane];
    }

    // ---- stage row-block: fully coalesced, 4 float4 in flight per thread ----
    const float4* g4 = (const float4*)(S + row0 * (long)KROW);
    #pragma unroll 1
    for (int j0 = 0; j0 < NV4; j0 += 1024) {
        float4 v[4];
        #pragma unroll
        for (int p = 0; p < 4; p++) {
            int j = j0 + p * 256 + tid;
            if (j < NV4) v[p] = g4[j];
        }
        #pragma unroll
        for (int p = 0; p < 4; p++) {
            int j = j0 + p * 256 + tid;
            if (j < NV4) *(float4*)&lds[4 * j] = v[p];
        }
    }
    // zero the garbage-read tail (taps there are zero, but 0*NaN != 0)
    if (tid < 4) *(float4*)&lds[ZTAIL + 4 * tid] = make_float4(0.f, 0.f, 0.f, 0.f);
    __syncthreads();

    // ---- compute: ds_read_b128 pairs + MFMA (verified k/lane mapping) ----
    const int n = lane & 31, h = lane >> 5;
    const int bbase = n * KROW + 8 * h;
    f32x16 acc = {};
    #pragma unroll
    for (int p = 0; p < 8; p++) {
        int u = u0 + p;
        if (u < u1) {
            float4 lo = *(const float4*)&lds[bbase + 16 * u];
            float4 hi = *(const float4*)&lds[bbase + 16 * u + 4];
            bf16x8 b;
            b[0] = (__bf16)lo.x; b[1] = (__bf16)lo.y;
            b[2] = (__bf16)lo.z; b[3] = (__bf16)lo.w;
            b[4] = (__bf16)hi.x; b[5] = (__bf16)hi.y;
            b[6] = (__bf16)hi.z; b[7] = (__bf16)hi.w;
            acc = __builtin_amdgcn_mfma_f32_32x32x16_bf16(af[p], b, acc, 0, 0, 0);
        }
    }

    // ---- cross-wave reduction (layout q*64+lane: conflict-free) ----
    __syncthreads();                          // tile data now dead
    if (w > 0) {
        float* rb = &lds[(w - 1) * 1024];
        #pragma unroll
        for (int q = 0; q < 16; q++) rb[q * 64 + lane] = acc[q];
    }
    __syncthreads();
    if (w == 0) {
        #pragma unroll
        for (int ww = 0; ww < 3; ww++) {
            const float* rb = &lds[ww * 1024];
            #pragma unroll
            for (int q = 0; q < 16; q++) acc[q] += rb[q * 64 + lane];
        }
        long t = row0 + n;                    // rows are exact: t < TDATA always
        #pragma unroll
        for (int r = 0; r < 16; r++) {
            int m = (r & 3) + 8 * (r >> 2) + 4 * h;
            if (m < SUB) inT[(long)m * SROW + 200 + t] = acc[r];
        }
    }
}

// ---------------------------------------------------------------------------
// Conv: block = (s, 2048 t's); swizzled LDS windows; sliding 16-float register
// window (8 new ds_reads per 8-tap group instead of 16); taps via LDS b128.
// ---------------------------------------------------------------------------
#define SW(i) ((i) + ((i) >> 5))

__global__ __launch_bounds__(256) void conv_kernel(
    const float* __restrict__ ws, float* __restrict__ out)
{
    __shared__ __align__(16) float W[2][2336];   // SW(2255)=2325 max
    __shared__ __align__(16) float HT[2][208];
    const int tid = threadIdx.x;
    const int s = blockIdx.y;
    const long t0 = (long)blockIdx.x * 2048;

    // stage windows: W[c][b] = row_c[t0 - 8 + b - 200pad ...] (same mapping as
    // verified round-3 kernel)
    for (int i = tid; i < 1128; i += 256) {
        int c = i >= 564;
        int i4 = i - c * 564;
        float4 v = *(const float4*)(ws + OFF_INT + (long)(c * SUB + s) * SROW
                                    + t0 - 8 + 4 * i4);
        int p = SW(4 * i4);                   // contiguous within aligned-4 runs
        W[c][p] = v.x; W[c][p + 1] = v.y; W[c][p + 2] = v.z; W[c][p + 3] = v.w;
    }
    if (tid < 104) {                          // taps: 2 channels x 208
        int c = tid >= 52;
        int j4 = (tid - c * 52) * 4;
        *(float4*)&HT[c][j4] =
            *(const float4*)(ws + OFF_HP + (c * SUB + s) * HROW + 8 + j4);
    }
    __syncthreads();

    float acc[8];
    #pragma unroll
    for (int r = 0; r < 8; r++) acc[r] = 0.f;

    #pragma unroll
    for (int c = 0; c < 2; c++) {
        const int xb0 = (tid << 3) + 200;
        float x[16];
        #pragma unroll
        for (int q = 0; q < 16; q++) x[q] = W[c][SW(xb0 + q)];
        #pragma unroll 2
        for (int g = 0; g < 26; g++) {
            float h[8];
            *(float4*)&h[0] = *(const float4*)&HT[c][g * 8];
            *(float4*)&h[4] = *(const float4*)&HT[c][g * 8 + 4];
            #pragma unroll
            for (int j = 0; j < 8; j++)
                #pragma unroll
                for (int r = 0; r < 8; r++)
                    acc[r] += h[j] * x[8 + r - j];
            if (g < 25) {                     // slide window down by 8
                float nx[8];
                #pragma unroll
                for (int q = 0; q < 8; q++)
                    nx[q] = W[c][SW(xb0 - 8 * (g + 1) + q)];
                #pragma unroll
                for (int q = 0; q < 8; q++) x[8 + q] = x[q];
                #pragma unroll
                for (int q = 0; q < 8; q++) x[q] = nx[q];
            }
        }
    }

    #pragma unroll
    for (int r = 0; r < 8; r++) {
        long t = t0 + 8 * tid + r;
        if (t < TDATA) out[t * SUB + s] = acc[r];
    }
}

// ---------------------------------------------------------------------------
extern "C" void kernel_launch(void* const* d_in, const int* in_sizes, int n_in,
                              void* d_out, int out_size, void* d_ws, size_t ws_size,
                              hipStream_t stream)
{
    const float* S_e     = (const float*)d_in[0];
    const float* S_i     = (const float*)d_in[1];
    const float* C_e     = (const float*)d_in[2];
    const float* C_i     = (const float*)d_in[3];
    const float* K_syn   = (const float*)d_in[4];
    const float* tau_syn = (const float*)d_in[5];
    const float* delta   = (const float*)d_in[6];
    float* out = (float*)d_out;
    float* ws  = (float*)d_ws;

    hipLaunchKernelGGL(setup_kernel, dim3(210), dim3(256), 0, stream,
                       C_e, C_i, K_syn, tau_syn, delta, ws);
    hipLaunchKernelGGL(gemm_kernel, dim3(2 * GEMM_BLKS), dim3(256), 0, stream,
                       S_e, S_i, ws);
    hipLaunchKernelGGL(conv_kernel, dim3(49, SUB), dim3(256), 0, stream,
                       ws, out);
}